// Round 6
// baseline (1731.806 us; speedup 1.0000x reference)
//
#include <hip/hip_runtime.h>
#include <hip/hip_bf16.h>
#include <stdint.h>

#define BATCH 32
#define CIN 128
#define HH 64
#define WW 64
#define MID 256
#define NCLS 65
#define HI 512
#define NWORDS 8   // 512 cols / 64 bits
#define HBS 260    // hb row stride
#define CHUNK 32   // edge-path channel staging chunk

// ---------------------------------------------------------------------------
// Transpose w1 [m][c][k] -> w1t [c*9+k][m] so conv weight loads coalesce.
// ---------------------------------------------------------------------------
__global__ __launch_bounds__(256) void transpose_w1(
    const float* __restrict__ w1, float* __restrict__ w1t)
{
    const int i = blockIdx.x * 256 + threadIdx.x;
    if (i >= MID * CIN * 9) return;
    const int ck = i >> 8;
    const int m  = i & 255;
    w1t[i] = w1[m * (CIN * 9) + ck];
}

// Row-FMA in the exact accumulation order used since round 3 (bit-exact).
template<int R>
__device__ __forceinline__ void row_fma(
    float v0, float v1, float v2, float v3, float v4, float v5,
    const float* __restrict__ w, float* __restrict__ acc)
{
    const float rv[6] = {v0, v1, v2, v3, v4, v5};
#pragma unroll
    for (int ky = 0; ky < 3; ++ky) {
        const int py = R - ky;
        if (py < 0 || py > 3) continue;
#pragma unroll
        for (int kx = 0; kx < 3; ++kx) {
            const float wv = w[ky * 3 + kx];
#pragma unroll
            for (int px = 0; px < 4; ++px)
                acc[py * 4 + px] = fmaf(rv[px + kx], wv, acc[py * 4 + px]);
        }
    }
}

#define SLD(dst, off) \
    asm volatile("s_load_dword %0, %1, " off : "=s"(dst) : "s"(base))

// ---------------------------------------------------------------------------
// Fused conv3x3+relu -> 1x1 conv -> softmax(65) -> pixel-shuffle -> threshold.
// Interior blocks: patch rows fetched via s_load (SMEM pipe, SGPRs) -- the
// patch is wave-uniform; LDS broadcast delivery was the round-5 bottleneck.
// Edge blocks: LDS staging in 32-channel chunks (xp = 4.6 KB).
// ---------------------------------------------------------------------------
__global__ __launch_bounds__(256) void head_kernel(
    const float* __restrict__ x, const float* __restrict__ w1t,
    const float* __restrict__ b1, const float* __restrict__ w2,
    const float* __restrict__ b2, float* __restrict__ out)
{
    const int b  = blockIdx.z;
    const int y0 = blockIdx.y * 4;
    const int x0 = blockIdx.x * 4;
    const int tid = threadIdx.x;

    __shared__ float xp[CHUNK * 36];    // edge staging chunk; sem overlays
    __shared__ float hb[16 * HBS];      // hidden acts [p][m]
    __shared__ float rinv[16];
    float* const sem = xp;              // 16*66 = 1056 <= 1152 floats

    const float* xb = x + (size_t)b * CIN * HH * WW;
    const float* wcol = w1t + tid;

    float acc[16];
    {
        const float bb = b1[tid];
#pragma unroll
        for (int p = 0; p < 16; ++p) acc[p] = bb;
    }

    const bool interior = blockIdx.x >= 1 && blockIdx.x <= 14 &&
                          blockIdx.y >= 1 && blockIdx.y <= 14;

    if (interior) {
        // patch window rows y0-1..y0+4, cols x0-1..x0+4, all in-bounds
        const float* base0 = xb + (y0 - 1) * WW + (x0 - 1);
        for (int c = 0; c < CIN; ++c) {
            float w[9];
#pragma unroll
            for (int k = 0; k < 9; ++k)
                w[k] = wcol[(c * 9 + k) * MID];     // lane-coalesced VMEM
            const float* base = base0 + c * (HH * WW);
            // rows 0..2 via scalar loads (offsets r*0x100 + k*4)
            float p00,p01,p02,p03,p04,p05, p10,p11,p12,p13,p14,p15,
                  p20,p21,p22,p23,p24,p25;
            SLD(p00,"0x000"); SLD(p01,"0x004"); SLD(p02,"0x008");
            SLD(p03,"0x00c"); SLD(p04,"0x010"); SLD(p05,"0x014");
            SLD(p10,"0x100"); SLD(p11,"0x104"); SLD(p12,"0x108");
            SLD(p13,"0x10c"); SLD(p14,"0x110"); SLD(p15,"0x114");
            SLD(p20,"0x200"); SLD(p21,"0x204"); SLD(p22,"0x208");
            SLD(p23,"0x20c"); SLD(p24,"0x210"); SLD(p25,"0x214");
            asm volatile("s_waitcnt lgkmcnt(0)"
                : "+s"(p00),"+s"(p01),"+s"(p02),"+s"(p03),"+s"(p04),"+s"(p05),
                  "+s"(p10),"+s"(p11),"+s"(p12),"+s"(p13),"+s"(p14),"+s"(p15),
                  "+s"(p20),"+s"(p21),"+s"(p22),"+s"(p23),"+s"(p24),"+s"(p25));
            row_fma<0>(p00,p01,p02,p03,p04,p05, w, acc);
            row_fma<1>(p10,p11,p12,p13,p14,p15, w, acc);
            row_fma<2>(p20,p21,p22,p23,p24,p25, w, acc);
            // rows 3..5
            float p30,p31,p32,p33,p34,p35, p40,p41,p42,p43,p44,p45,
                  p50,p51,p52,p53,p54,p55;
            SLD(p30,"0x300"); SLD(p31,"0x304"); SLD(p32,"0x308");
            SLD(p33,"0x30c"); SLD(p34,"0x310"); SLD(p35,"0x314");
            SLD(p40,"0x400"); SLD(p41,"0x404"); SLD(p42,"0x408");
            SLD(p43,"0x40c"); SLD(p44,"0x410"); SLD(p45,"0x414");
            SLD(p50,"0x500"); SLD(p51,"0x504"); SLD(p52,"0x508");
            SLD(p53,"0x50c"); SLD(p54,"0x510"); SLD(p55,"0x514");
            asm volatile("s_waitcnt lgkmcnt(0)"
                : "+s"(p30),"+s"(p31),"+s"(p32),"+s"(p33),"+s"(p34),"+s"(p35),
                  "+s"(p40),"+s"(p41),"+s"(p42),"+s"(p43),"+s"(p44),"+s"(p45),
                  "+s"(p50),"+s"(p51),"+s"(p52),"+s"(p53),"+s"(p54),"+s"(p55));
            row_fma<3>(p30,p31,p32,p33,p34,p35, w, acc);
            row_fma<4>(p40,p41,p42,p43,p44,p45, w, acc);
            row_fma<5>(p50,p51,p52,p53,p54,p55, w, acc);
        }
    } else {
        // edge path: LDS staging, 32-channel chunks (R5 logic, chunked)
        for (int c0 = 0; c0 < CIN; c0 += CHUNK) {
            __syncthreads();
            for (int i = tid; i < CHUNK * 36; i += 256) {
                int ci = i / 36, r = i % 36;
                int yy = y0 - 1 + (r / 6), xx = x0 - 1 + (r % 6);
                float v = 0.f;
                if ((unsigned)yy < HH && (unsigned)xx < WW)
                    v = xb[((c0 + ci) * HH + yy) * WW + xx];
                xp[i] = v;
            }
            __syncthreads();
            for (int ci = 0; ci < CHUNK; ++ci) {
                const int c = c0 + ci;
                float w[9];
#pragma unroll
                for (int k = 0; k < 9; ++k)
                    w[k] = wcol[(c * 9 + k) * MID];
                const float* row = xp + ci * 36;
#pragma unroll
                for (int r = 0; r < 6; ++r) {
                    const float2 q0 = *(const float2*)(row + r * 6);
                    const float2 q1 = *(const float2*)(row + r * 6 + 2);
                    const float2 q2 = *(const float2*)(row + r * 6 + 4);
                    const float rv[6] = {q0.x,q0.y,q1.x,q1.y,q2.x,q2.y};
#pragma unroll
                    for (int ky = 0; ky < 3; ++ky) {
                        const int py = r - ky;
                        if (py < 0 || py > 3) continue;
#pragma unroll
                        for (int kx = 0; kx < 3; ++kx) {
                            const float wv = w[ky * 3 + kx];
#pragma unroll
                            for (int px = 0; px < 4; ++px)
                                acc[py * 4 + px] =
                                    fmaf(rv[px + kx], wv, acc[py * 4 + px]);
                        }
                    }
                }
            }
        }
    }

#pragma unroll
    for (int p = 0; p < 16; ++p)
        hb[p * HBS + tid] = fmaxf(acc[p], 0.f);
    __syncthreads();

    // ---- 1x1 conv: thread (p = tid&15, g = tid>>4) does o = 4g..4g+3 ----
    {
        const int p = tid & 15, g = tid >> 4;
        float a[4];
#pragma unroll
        for (int j = 0; j < 4; ++j) a[j] = b2[g * 4 + j];
        const float* hrow = hb + p * HBS;
        const float* w2r = w2 + (size_t)(g * 4) * MID;
        for (int mm = 0; mm < MID; mm += 4) {
            const float4 h4 = *(const float4*)(hrow + mm);
#pragma unroll
            for (int j = 0; j < 4; ++j) {
                const float4 w4 = *(const float4*)(w2r + j * MID + mm);
                a[j] = fmaf(h4.x, w4.x, a[j]);
                a[j] = fmaf(h4.y, w4.y, a[j]);
                a[j] = fmaf(h4.z, w4.z, a[j]);
                a[j] = fmaf(h4.w, w4.w, a[j]);
            }
        }
        __syncthreads();                 // xp reads done; safe to write sem
#pragma unroll
        for (int j = 0; j < 4; ++j) sem[p * 66 + g * 4 + j] = a[j];
        if (tid < 16) {                  // dust class o=64
            float ad = b2[64];
            const float* wd = w2 + (size_t)64 * MID;
            const float* hr = hb + tid * HBS;
            for (int mm = 0; mm < MID; mm += 4) {
                const float4 h4 = *(const float4*)(hr + mm);
                const float4 w4 = *(const float4*)(wd + mm);
                ad = fmaf(h4.x, w4.x, ad);
                ad = fmaf(h4.y, w4.y, ad);
                ad = fmaf(h4.z, w4.z, ad);
                ad = fmaf(h4.w, w4.w, ad);
            }
            sem[tid * 66 + 64] = ad;
        }
    }
    __syncthreads();

    // ---- softmax per pixel: 4 lanes per pixel ----
    if (tid < 64) {
        const int p = tid >> 2, q = tid & 3;
        const int o0 = q * 17;
        const int o1 = (o0 + 17 < NCLS) ? o0 + 17 : NCLS;
        float mx = -1e30f;
        for (int o = o0; o < o1; ++o) mx = fmaxf(mx, sem[p * 66 + o]);
        mx = fmaxf(mx, __shfl_xor(mx, 1));
        mx = fmaxf(mx, __shfl_xor(mx, 2));
        float s = 0.f;
        for (int o = o0; o < o1; ++o) {
            float e = __expf(sem[p * 66 + o] - mx);
            sem[p * 66 + o] = e;
            s += e;
        }
        s += __shfl_xor(s, 1);
        s += __shfl_xor(s, 2);
        if (q == 0) rinv[p] = 1.f / s;
    }
    __syncthreads();

    // ---- pixel-shuffle write with conf threshold (classes 0..63) ----
    for (int t = tid; t < 16 * 64; t += 256) {
        const int p = t >> 6, o = t & 63;
        float v = sem[p * 66 + o] * rinv[p];
        if (!(v >= 0.015f)) v = 0.f;
        const int py = p >> 2, px = p & 3;
        const int row = (y0 + py) * 8 + (o >> 3);
        const int col = (x0 + px) * 8 + (o & 7);
        out[((size_t)b * HI + row) * HI + col] = v;
    }
}

// ---------------------------------------------------------------------------
// One NMS iteration, bit-packed masks. Min==nullptr => zero mask => init.
// ---------------------------------------------------------------------------
__global__ __launch_bounds__(256) void nms_iter(
    const float* __restrict__ S, const uint64_t* __restrict__ Min,
    uint64_t* __restrict__ Mout)
{
    const int b = blockIdx.z;
    const int bx = blockIdx.x;
    const int ty = blockIdx.y * 64, tx = bx * 64;
    const int tid = threadIdx.x;

    __shared__ uint64_t smw[80 * 3];
    __shared__ uint64_t hd[80 * 3];
    __shared__ uint64_t sup[72 * 3];
    __shared__ __align__(16) float sfl[72 * 76];
    __shared__ __align__(16) float rm[72 * 64];

    if (tid < 240) {
        const int i = tid / 3, j = tid % 3;
        const int yy = ty - 8 + i;
        const int wj = bx - 1 + j;
        uint64_t v = 0;
        if (Min && (unsigned)yy < HI && (unsigned)wj < NWORDS)
            v = Min[((size_t)b * HI + yy) * NWORDS + wj];
        smw[tid] = v;
    }
    __syncthreads();
    if (tid < 240) {
        const int i = tid / 3, j = tid % 3;
        const uint64_t c = smw[i * 3 + j];
        const uint64_t l = j > 0 ? smw[i * 3 + j - 1] : 0ull;
        const uint64_t r = j < 2 ? smw[i * 3 + j + 1] : 0ull;
        uint64_t d = c;
#pragma unroll
        for (int s = 1; s <= 4; ++s)
            d |= (c >> s) | (r << (64 - s)) | (c << s) | (l >> (64 - s));
        hd[tid] = d;
    }
    __syncthreads();
    if (tid < 216) {
        const int r = tid / 3, j = tid % 3;
        uint64_t v = 0;
#pragma unroll
        for (int k = 0; k < 9; ++k) v |= hd[(r + k) * 3 + j];
        sup[tid] = v;
    }
    __syncthreads();
    const float* Sb = S + (size_t)b * HI * HI;
    for (int k = tid; k < 72 * 18; k += 256) {
        const int r = k / 18, f4 = k % 18;
        const int gy = ty - 4 + r;
        const int gx0 = tx - 4 + f4 * 4;
        float4 v = make_float4(0.f, 0.f, 0.f, 0.f);
        float* pv = (float*)&v;
        if ((unsigned)gy < HI) {
            if (gx0 >= 0 && gx0 + 3 < HI)
                v = *(const float4*)(Sb + (size_t)gy * HI + gx0);
            else {
#pragma unroll
                for (int cc = 0; cc < 4; ++cc)
                    if ((unsigned)(gx0 + cc) < HI)
                        pv[cc] = Sb[(size_t)gy * HI + gx0 + cc];
            }
        }
        const int rel64 = 60 + 4 * f4;
        const uint64_t w = sup[r * 3 + (rel64 >> 6)];
        const int b0 = rel64 & 63;
#pragma unroll
        for (int cc = 0; cc < 4; ++cc)
            if ((w >> (b0 + cc)) & 1ull) pv[cc] = 0.f;
        *(float4*)(sfl + r * 76 + f4 * 4) = v;
    }
    __syncthreads();
    for (int k = tid; k < 72 * 16; k += 256) {
        const int r = k / 16, x4 = (k % 16) * 4;
        const float4 a  = *(const float4*)(sfl + r * 76 + x4);
        const float4 bq = *(const float4*)(sfl + r * 76 + x4 + 4);
        const float4 cq = *(const float4*)(sfl + r * 76 + x4 + 8);
        const float v0=a.x,v1=a.y,v2=a.z,v3=a.w;
        const float v4=bq.x,v5=bq.y,v6=bq.z,v7=bq.w;
        const float v8=cq.x,v9=cq.y,v10=cq.z,v11=cq.w;
        const float m4567 = fmaxf(fmaxf(v4,v5), fmaxf(v6,v7));
        const float m23 = fmaxf(v2,v3), m89 = fmaxf(v8,v9);
        const float o0 = fmaxf(fmaxf(fmaxf(v0,v1), m23), fmaxf(m4567, v8));
        const float o1 = fmaxf(fmaxf(v1, m23), fmaxf(m4567, m89));
        const float o2 = fmaxf(fmaxf(m23, m4567), fmaxf(m89, v10));
        const float o3 = fmaxf(fmaxf(v3, m4567), fmaxf(fmaxf(m89, v10), v11));
        *(float4*)(rm + r * 64 + x4) = make_float4(o0,o1,o2,o3);
    }
    __syncthreads();
    {
        const int wv = tid >> 6, lane = tid & 63;
        const int ybase = wv * 16;
        float ring[9];
#pragma unroll
        for (int k = 0; k < 8; ++k) ring[k] = rm[(ybase + k) * 64 + lane];
#pragma unroll
        for (int q = 0; q < 16; ++q) {
            const int y = ybase + q;
            ring[(q + 8) % 9] = rm[(y + 8) * 64 + lane];
            float mv = ring[0];
#pragma unroll
            for (int k = 1; k < 9; ++k) mv = fmaxf(mv, ring[k]);
            const float c = sfl[(y + 4) * 76 + lane + 4];
            const uint64_t oldw = smw[(y + 8) * 3 + 1];
            const bool keep = ((oldw >> lane) & 1ull) || (c == mv && c > 0.f);
            const uint64_t word = __ballot(keep);
            if (lane == 0)
                Mout[((size_t)b * HI + ty + y) * NWORDS + bx] = word;
        }
    }
}

// ---------------------------------------------------------------------------
// Finalize: out = (Mbit && border) ? S : 0, in place on d_out.
// ---------------------------------------------------------------------------
__global__ __launch_bounds__(256) void finalize_bits(
    float* __restrict__ S, const uint64_t* __restrict__ Mw)
{
    const int i4 = blockIdx.x * 256 + threadIdx.x;
    const size_t base = (size_t)i4 * 4;
    const int x = (int)(base & 511);
    const int y = (int)((base >> 9) & 511);
    const int bb = (int)(base >> 18);
    const uint64_t w = Mw[((size_t)bb * HI + y) * NWORDS + (x >> 6)];
    float4 v = ((const float4*)S)[i4];
    float* pv = (float*)&v;
    const bool rowok = (y >= 4) && (y < HI - 4);
#pragma unroll
    for (int cc = 0; cc < 4; ++cc) {
        const int xx = x + cc;
        const bool keep = rowok && (xx >= 4) && (xx < HI - 4) &&
                          ((w >> (xx & 63)) & 1ull);
        if (!keep) pv[cc] = 0.f;
    }
    ((float4*)S)[i4] = v;
}

extern "C" void kernel_launch(void* const* d_in, const int* in_sizes, int n_in,
                              void* d_out, int out_size, void* d_ws, size_t ws_size,
                              hipStream_t stream) {
    const float* x  = (const float*)d_in[0];
    const float* w1 = (const float*)d_in[1];
    const float* b1 = (const float*)d_in[2];
    const float* w2 = (const float*)d_in[3];
    const float* b2 = (const float*)d_in[4];
    float* out = (float*)d_out;

    float* w1t = (float*)d_ws;
    uint64_t* MA = (uint64_t*)((char*)d_ws + (2u << 20));
    uint64_t* MB = MA + (size_t)BATCH * HI * NWORDS;

    transpose_w1<<<(MID * CIN * 9 + 255) / 256, 256, 0, stream>>>(w1, w1t);
    head_kernel<<<dim3(16, 16, BATCH), 256, 0, stream>>>(x, w1t, b1, w2, b2, out);

    dim3 g(NWORDS, 8, BATCH);
    nms_iter<<<g, 256, 0, stream>>>(out, nullptr, MA);   // init (zero mask)
    for (int it = 0; it < 4; ++it) {                     // 8 iterations
        nms_iter<<<g, 256, 0, stream>>>(out, MA, MB);
        nms_iter<<<g, 256, 0, stream>>>(out, MB, MA);
    }
    const int nf4 = BATCH * HI * HI / 4;
    finalize_bits<<<nf4 / 256, 256, 0, stream>>>(out, MA);
}

// Round 7
// 597.259 us; speedup vs baseline: 2.8996x; 2.8996x over previous
//
#include <hip/hip_runtime.h>
#include <hip/hip_bf16.h>
#include <stdint.h>

#define BATCH 32
#define CIN 128
#define HH 64
#define WW 64
#define MID 256
#define NCLS 65
#define HI 512
#define NWORDS 8      // 512 cols / 64 bits
#define XPS 136       // xps row stride (halfs): 16B-aligned b128, minimal conflicts
#define HBS2 264      // hb row stride (halfs)
#define SEMS 68       // sem row stride (floats)

typedef _Float16 half8 __attribute__((ext_vector_type(8)));
typedef _Float16 half4v __attribute__((ext_vector_type(4)));
typedef _Float16 half2v __attribute__((ext_vector_type(2)));
typedef float f32x4 __attribute__((ext_vector_type(4)));

// ---------------------------------------------------------------------------
// Pack w1 [m][c][ky][kx] into MFMA A-fragment layout, f16 hi/lo split.
// Index: (((kix*4 + s)*16 + mt)*64 + lane)*8 + j
//   m = mt*16 + (lane&15); c = s*32 + (lane>>4)*8 + j; (ky,kx) = kix/3,kix%3
// ---------------------------------------------------------------------------
__global__ __launch_bounds__(256) void prep_w1f(
    const float* __restrict__ w1, _Float16* __restrict__ w1fh,
    _Float16* __restrict__ w1fl)
{
    const int idx = blockIdx.x * 256 + threadIdx.x;   // < 294912
    const int j = idx & 7, lane = (idx >> 3) & 63, mt = (idx >> 9) & 15;
    const int s = (idx >> 13) & 3, kix = idx >> 15;
    const int m = mt * 16 + (lane & 15);
    const int c = s * 32 + (lane >> 4) * 8 + j;
    const int ky = kix / 3, kx = kix - ky * 3;
    const float v = w1[((m * CIN + c) * 3 + ky) * 3 + kx];
    const _Float16 hi = (_Float16)v;
    w1fh[idx] = hi;
    w1fl[idx] = (_Float16)(v - (float)hi);
}

// ---------------------------------------------------------------------------
// Pack w2 [o][m] into MFMA A-fragment layout (o padded 65->80), f16 hi/lo.
// Index: ((mt*8 + ks)*64 + lane)*8 + j ; o = mt*16+(lane&15); k = ks*32+q*8+j
// ---------------------------------------------------------------------------
__global__ __launch_bounds__(256) void prep_w2f(
    const float* __restrict__ w2, _Float16* __restrict__ w2fh,
    _Float16* __restrict__ w2fl)
{
    const int idx = blockIdx.x * 256 + threadIdx.x;   // < 20480
    const int j = idx & 7, lane = (idx >> 3) & 63;
    const int ks = (idx >> 9) & 7, mt = idx >> 12;
    const int o = mt * 16 + (lane & 15);
    const int k = ks * 32 + (lane >> 4) * 8 + j;
    const float v = (o < NCLS) ? w2[o * MID + k] : 0.f;
    const _Float16 hi = (_Float16)v;
    w2fh[idx] = hi;
    w2fl[idx] = (_Float16)(v - (float)hi);
}

// ---------------------------------------------------------------------------
// MFMA head: conv3x3 (9 shifted GEMMs, f16 3-product split ~= fp32 exact)
// + bias + relu -> 1x1 MFMA -> softmax(65) -> shuffle -> threshold.
// Block: 256 thr (4 waves), 8x8 pixel tile. Wave w owns mids 64w..64w+63.
// MFMA 16x16x32_f16: A[m=lane&15][k=q*8+j], B[k=q*8+j][n=lane&15],
// C/D: n=lane&15, m=q*4+reg.
// ---------------------------------------------------------------------------
__global__ __launch_bounds__(256) void head_kernel(
    const float* __restrict__ x,
    const _Float16* __restrict__ w1fh, const _Float16* __restrict__ w1fl,
    const _Float16* __restrict__ w2fh, const _Float16* __restrict__ w2fl,
    const float* __restrict__ b1, const float* __restrict__ b2,
    float* __restrict__ out)
{
    const int b  = blockIdx.z;
    const int y0 = blockIdx.y * 8, x0 = blockIdx.x * 8;
    const int tid = threadIdx.x;
    const int lane = tid & 63, w = tid >> 6;
    const int n = lane & 15, q = lane >> 4;

    __shared__ __align__(16) unsigned char SM[54400];
    _Float16* const xh = (_Float16*)SM;            // [100][XPS]
    _Float16* const xl = xh + 100 * XPS;
    _Float16* const hbh = (_Float16*)SM;           // [32][HBS2] (overlays xps)
    _Float16* const hbl = hbh + 32 * HBS2;
    float* const sem  = (float*)(SM + 33792);      // [32][SEMS]
    float* const rinv = sem + 32 * SEMS;           // [32]

    // ---- stage patch (10x10, zero-pad OOB) as f16 hi/lo, [pos][c] ----
    const float* xb = x + (size_t)b * CIN * HH * WW;
    for (int i = tid; i < 6400; i += 256) {
        const int c2 = i / 100, pos = i - c2 * 100;
        const int r = pos / 10, cc = pos - r * 10;
        const int gy = y0 - 1 + r, gx = x0 - 1 + cc;
        const int c = c2 * 2;
        float v0 = 0.f, v1 = 0.f;
        if ((unsigned)gy < HH && (unsigned)gx < WW) {
            const float* p = xb + (c * HH + gy) * WW + gx;
            v0 = p[0]; v1 = p[HH * WW];
        }
        const _Float16 h0 = (_Float16)v0, h1 = (_Float16)v1;
        half2v hi = {h0, h1};
        half2v lo = {(_Float16)(v0 - (float)h0), (_Float16)(v1 - (float)h1)};
        *(half2v*)(xh + pos * XPS + c) = hi;
        *(half2v*)(xl + pos * XPS + c) = lo;
    }
    __syncthreads();

    // ---- conv: 9 shifted GEMMs, K=128 each ----
    f32x4 acc[4][4];   // [mtile][ntile]
#pragma unroll
    for (int i = 0; i < 4; ++i)
#pragma unroll
        for (int t = 0; t < 4; ++t) acc[i][t] = (f32x4){0.f, 0.f, 0.f, 0.f};

    int bposT[4];
#pragma unroll
    for (int t = 0; t < 4; ++t)
        bposT[t] = (t * 2 + (n >> 3)) * 10 + (n & 7);   // pixel base pos

    for (int kix = 0; kix < 9; ++kix) {
        const int ky = kix / 3;
        const int koff = ky * 10 + (kix - ky * 3);      // ky*10+kx
#pragma unroll
        for (int s = 0; s < 4; ++s) {
            half8 Ah[4], Al[4];
#pragma unroll
            for (int i = 0; i < 4; ++i) {
                const size_t o = (size_t)(kix * 4 + s) * 8192 +
                                 (w * 4 + i) * 512 + lane * 8;
                Ah[i] = *(const half8*)(w1fh + o);
                Al[i] = *(const half8*)(w1fl + o);
            }
            half8 Bh[4], Bl[4];
#pragma unroll
            for (int t = 0; t < 4; ++t) {
                const int a = (bposT[t] + koff) * XPS + s * 32 + q * 8;
                Bh[t] = *(const half8*)(xh + a);
                Bl[t] = *(const half8*)(xl + a);
            }
#pragma unroll
            for (int i = 0; i < 4; ++i)
#pragma unroll
                for (int t = 0; t < 4; ++t) {
                    acc[i][t] = __builtin_amdgcn_mfma_f32_16x16x32_f16(
                        Ah[i], Bh[t], acc[i][t], 0, 0, 0);
                    acc[i][t] = __builtin_amdgcn_mfma_f32_16x16x32_f16(
                        Ah[i], Bl[t], acc[i][t], 0, 0, 0);
                    acc[i][t] = __builtin_amdgcn_mfma_f32_16x16x32_f16(
                        Al[i], Bh[t], acc[i][t], 0, 0, 0);
                }
        }
    }
    __syncthreads();    // xps dead; hb may overlay

    // ---- epilogue in two 32-pixel halves (keeps LDS <= 54.4 KB) ----
    for (int hf = 0; hf < 2; ++hf) {
        if (hf) __syncthreads();
        // write hb (f16 split) with bias+relu
#pragma unroll
        for (int i = 0; i < 4; ++i)
#pragma unroll
            for (int tt = 0; tt < 2; ++tt) {
                const int t = hf * 2 + tt;
                const int p = tt * 16 + n;
                const int m0 = w * 64 + i * 16 + q * 4;
                const f32x4 a = acc[i][t];
                const float4 bv = *(const float4*)(b1 + m0);
                const float h0 = fmaxf(a[0] + bv.x, 0.f);
                const float h1 = fmaxf(a[1] + bv.y, 0.f);
                const float h2 = fmaxf(a[2] + bv.z, 0.f);
                const float h3 = fmaxf(a[3] + bv.w, 0.f);
                half4v hh = {(_Float16)h0, (_Float16)h1,
                             (_Float16)h2, (_Float16)h3};
                half4v hl = {(_Float16)(h0 - (float)hh[0]),
                             (_Float16)(h1 - (float)hh[1]),
                             (_Float16)(h2 - (float)hh[2]),
                             (_Float16)(h3 - (float)hh[3])};
                *(half4v*)(hbh + p * HBS2 + m0) = hh;
                *(half4v*)(hbl + p * HBS2 + m0) = hl;
            }
        __syncthreads();
        // 1x1 via MFMA: M=80 (5 mtiles, rows>=65 zero), K=256, N=32
        {
            const int nt = w & 1;
            const int mt0 = (w < 2) ? 0 : 3;
            const int nmt = (w < 2) ? 3 : 2;
            const int pb = nt * 16 + n;
            f32x4 a2[3];
#pragma unroll
            for (int j = 0; j < 3; ++j) a2[j] = (f32x4){0.f, 0.f, 0.f, 0.f};
#pragma unroll
            for (int ks = 0; ks < 8; ++ks) {
                const int ad = pb * HBS2 + ks * 32 + q * 8;
                const half8 B2h = *(const half8*)(hbh + ad);
                const half8 B2l = *(const half8*)(hbl + ad);
#pragma unroll
                for (int j = 0; j < 3; ++j)
                    if (j < nmt) {
                        const size_t o = (size_t)((mt0 + j) * 8 + ks) * 512 +
                                         lane * 8;
                        const half8 A2h = *(const half8*)(w2fh + o);
                        const half8 A2l = *(const half8*)(w2fl + o);
                        a2[j] = __builtin_amdgcn_mfma_f32_16x16x32_f16(
                            A2h, B2h, a2[j], 0, 0, 0);
                        a2[j] = __builtin_amdgcn_mfma_f32_16x16x32_f16(
                            A2h, B2l, a2[j], 0, 0, 0);
                        a2[j] = __builtin_amdgcn_mfma_f32_16x16x32_f16(
                            A2l, B2h, a2[j], 0, 0, 0);
                    }
            }
#pragma unroll
            for (int j = 0; j < 3; ++j)
                if (j < nmt) {
                    const int o0 = (mt0 + j) * 16 + q * 4;
#pragma unroll
                    for (int r2 = 0; r2 < 4; ++r2) {
                        const int o = o0 + r2;
                        if (o < NCLS)
                            sem[pb * SEMS + o] = a2[j][r2] + b2[o];
                    }
                }
        }
        __syncthreads();
        // softmax per pixel (4 lanes per pixel)
        if (tid < 128) {
            const int p = tid >> 2, q4 = tid & 3;
            const int o0 = q4 * 17;
            const int o1 = (o0 + 17 < NCLS) ? o0 + 17 : NCLS;
            float mx = -1e30f;
            for (int o = o0; o < o1; ++o)
                mx = fmaxf(mx, sem[p * SEMS + o]);
            mx = fmaxf(mx, __shfl_xor(mx, 1));
            mx = fmaxf(mx, __shfl_xor(mx, 2));
            float ssum = 0.f;
            for (int o = o0; o < o1; ++o) {
                float e = __expf(sem[p * SEMS + o] - mx);
                sem[p * SEMS + o] = e;
                ssum += e;
            }
            ssum += __shfl_xor(ssum, 1);
            ssum += __shfl_xor(ssum, 2);
            if (q4 == 0) rinv[p] = 1.f / ssum;
        }
        __syncthreads();
        // shuffle + threshold store (32 px x 64 classes)
        for (int t2 = tid; t2 < 2048; t2 += 256) {
            const int p = t2 >> 6, o = t2 & 63;
            float v = sem[p * SEMS + o] * rinv[p];
            if (!(v >= 0.015f)) v = 0.f;
            const int P = hf * 32 + p;
            const int py = P >> 3, px = P & 7;
            const int row = (y0 + py) * 8 + (o >> 3);
            const int col = (x0 + px) * 8 + (o & 7);
            out[((size_t)b * HI + row) * HI + col] = v;
        }
    }
}

// ---------------------------------------------------------------------------
// One NMS iteration, bit-packed masks. Min==nullptr => zero mask => init.
// ---------------------------------------------------------------------------
__global__ __launch_bounds__(256) void nms_iter(
    const float* __restrict__ S, const uint64_t* __restrict__ Min,
    uint64_t* __restrict__ Mout)
{
    const int b = blockIdx.z;
    const int bx = blockIdx.x;
    const int ty = blockIdx.y * 64, tx = bx * 64;
    const int tid = threadIdx.x;

    __shared__ uint64_t smw[80 * 3];
    __shared__ uint64_t hd[80 * 3];
    __shared__ uint64_t sup[72 * 3];
    __shared__ __align__(16) float sfl[72 * 76];
    __shared__ __align__(16) float rm[72 * 64];

    if (tid < 240) {
        const int i = tid / 3, j = tid % 3;
        const int yy = ty - 8 + i;
        const int wj = bx - 1 + j;
        uint64_t v = 0;
        if (Min && (unsigned)yy < HI && (unsigned)wj < NWORDS)
            v = Min[((size_t)b * HI + yy) * NWORDS + wj];
        smw[tid] = v;
    }
    __syncthreads();
    if (tid < 240) {
        const int i = tid / 3, j = tid % 3;
        const uint64_t c = smw[i * 3 + j];
        const uint64_t l = j > 0 ? smw[i * 3 + j - 1] : 0ull;
        const uint64_t r = j < 2 ? smw[i * 3 + j + 1] : 0ull;
        uint64_t d = c;
#pragma unroll
        for (int s = 1; s <= 4; ++s)
            d |= (c >> s) | (r << (64 - s)) | (c << s) | (l >> (64 - s));
        hd[tid] = d;
    }
    __syncthreads();
    if (tid < 216) {
        const int r = tid / 3, j = tid % 3;
        uint64_t v = 0;
#pragma unroll
        for (int k = 0; k < 9; ++k) v |= hd[(r + k) * 3 + j];
        sup[tid] = v;
    }
    __syncthreads();
    const float* Sb = S + (size_t)b * HI * HI;
    for (int k = tid; k < 72 * 18; k += 256) {
        const int r = k / 18, f4 = k % 18;
        const int gy = ty - 4 + r;
        const int gx0 = tx - 4 + f4 * 4;
        float4 v = make_float4(0.f, 0.f, 0.f, 0.f);
        float* pv = (float*)&v;
        if ((unsigned)gy < HI) {
            if (gx0 >= 0 && gx0 + 3 < HI)
                v = *(const float4*)(Sb + (size_t)gy * HI + gx0);
            else {
#pragma unroll
                for (int cc = 0; cc < 4; ++cc)
                    if ((unsigned)(gx0 + cc) < HI)
                        pv[cc] = Sb[(size_t)gy * HI + gx0 + cc];
            }
        }
        const int rel64 = 60 + 4 * f4;
        const uint64_t w = sup[r * 3 + (rel64 >> 6)];
        const int b0 = rel64 & 63;
#pragma unroll
        for (int cc = 0; cc < 4; ++cc)
            if ((w >> (b0 + cc)) & 1ull) pv[cc] = 0.f;
        *(float4*)(sfl + r * 76 + f4 * 4) = v;
    }
    __syncthreads();
    for (int k = tid; k < 72 * 16; k += 256) {
        const int r = k / 16, x4 = (k % 16) * 4;
        const float4 a  = *(const float4*)(sfl + r * 76 + x4);
        const float4 bq = *(const float4*)(sfl + r * 76 + x4 + 4);
        const float4 cq = *(const float4*)(sfl + r * 76 + x4 + 8);
        const float v0=a.x,v1=a.y,v2=a.z,v3=a.w;
        const float v4=bq.x,v5=bq.y,v6=bq.z,v7=bq.w;
        const float v8=cq.x,v9=cq.y,v10=cq.z,v11=cq.w;
        const float m4567 = fmaxf(fmaxf(v4,v5), fmaxf(v6,v7));
        const float m23 = fmaxf(v2,v3), m89 = fmaxf(v8,v9);
        const float o0 = fmaxf(fmaxf(fmaxf(v0,v1), m23), fmaxf(m4567, v8));
        const float o1 = fmaxf(fmaxf(v1, m23), fmaxf(m4567, m89));
        const float o2 = fmaxf(fmaxf(m23, m4567), fmaxf(m89, v10));
        const float o3 = fmaxf(fmaxf(v3, m4567), fmaxf(fmaxf(m89, v10), v11));
        *(float4*)(rm + r * 64 + x4) = make_float4(o0,o1,o2,o3);
    }
    __syncthreads();
    {
        const int wv = tid >> 6, lane = tid & 63;
        const int ybase = wv * 16;
        float ring[9];
#pragma unroll
        for (int k = 0; k < 8; ++k) ring[k] = rm[(ybase + k) * 64 + lane];
#pragma unroll
        for (int qq = 0; qq < 16; ++qq) {
            const int y = ybase + qq;
            ring[(qq + 8) % 9] = rm[(y + 8) * 64 + lane];
            float mv = ring[0];
#pragma unroll
            for (int k = 1; k < 9; ++k) mv = fmaxf(mv, ring[k]);
            const float c = sfl[(y + 4) * 76 + lane + 4];
            const uint64_t oldw = smw[(y + 8) * 3 + 1];
            const bool keep = ((oldw >> lane) & 1ull) || (c == mv && c > 0.f);
            const uint64_t word = __ballot(keep);
            if (lane == 0)
                Mout[((size_t)b * HI + ty + y) * NWORDS + bx] = word;
        }
    }
}

// ---------------------------------------------------------------------------
// Finalize: out = (Mbit && border) ? S : 0, in place on d_out.
// ---------------------------------------------------------------------------
__global__ __launch_bounds__(256) void finalize_bits(
    float* __restrict__ S, const uint64_t* __restrict__ Mw)
{
    const int i4 = blockIdx.x * 256 + threadIdx.x;
    const size_t base = (size_t)i4 * 4;
    const int x = (int)(base & 511);
    const int y = (int)((base >> 9) & 511);
    const int bb = (int)(base >> 18);
    const uint64_t w = Mw[((size_t)bb * HI + y) * NWORDS + (x >> 6)];
    float4 v = ((const float4*)S)[i4];
    float* pv = (float*)&v;
    const bool rowok = (y >= 4) && (y < HI - 4);
#pragma unroll
    for (int cc = 0; cc < 4; ++cc) {
        const int xx = x + cc;
        const bool keep = rowok && (xx >= 4) && (xx < HI - 4) &&
                          ((w >> (xx & 63)) & 1ull);
        if (!keep) pv[cc] = 0.f;
    }
    ((float4*)S)[i4] = v;
}

extern "C" void kernel_launch(void* const* d_in, const int* in_sizes, int n_in,
                              void* d_out, int out_size, void* d_ws, size_t ws_size,
                              hipStream_t stream) {
    const float* x  = (const float*)d_in[0];
    const float* w1 = (const float*)d_in[1];
    const float* b1 = (const float*)d_in[2];
    const float* w2 = (const float*)d_in[3];
    const float* b2 = (const float*)d_in[4];
    float* out = (float*)d_out;

    // ws: w1f_hi | w1f_lo (589824 B each) | w2f_hi | w2f_lo | MA | MB
    char* wsb = (char*)d_ws;
    _Float16* w1fh = (_Float16*)(wsb);
    _Float16* w1fl = (_Float16*)(wsb + 0x90000);
    _Float16* w2fh = (_Float16*)(wsb + 0x120000);
    _Float16* w2fl = (_Float16*)(wsb + 0x130000);
    uint64_t* MA   = (uint64_t*)(wsb + 0x140000);
    uint64_t* MB   = (uint64_t*)(wsb + 0x240000);

    prep_w1f<<<294912 / 256, 256, 0, stream>>>(w1, w1fh, w1fl);
    prep_w2f<<<20480 / 256, 256, 0, stream>>>(w2, w2fh, w2fl);
    head_kernel<<<dim3(8, 8, BATCH), 256, 0, stream>>>(
        x, w1fh, w1fl, w2fh, w2fl, b1, b2, out);

    dim3 g(NWORDS, 8, BATCH);
    nms_iter<<<g, 256, 0, stream>>>(out, nullptr, MA);   // init (zero mask)
    for (int it = 0; it < 4; ++it) {                     // 8 iterations
        nms_iter<<<g, 256, 0, stream>>>(out, MA, MB);
        nms_iter<<<g, 256, 0, stream>>>(out, MB, MA);
    }
    const int nf4 = BATCH * HI * HI / 4;
    finalize_bits<<<nf4 / 256, 256, 0, stream>>>(out, MA);
}